// Round 5
// baseline (432.765 us; speedup 1.0000x reference)
//
#include <hip/hip_runtime.h>
#include <hip/hip_bf16.h>

#define BDIM 256
#define NROW 64      // S = O = 64
#define DDIM 512
#define FDIM 32
#define BBATCH 32
#define NBLK (FDIM * BBATCH)

typedef short bf16x8 __attribute__((ext_vector_type(8)));
typedef float f32x4 __attribute__((ext_vector_type(4)));

__device__ __forceinline__ unsigned short f2bf(float f) {
    unsigned int u = __float_as_uint(f);
    u += 0x7FFFu + ((u >> 16) & 1u);   // round-to-nearest-even
    return (unsigned short)(u >> 16);
}

__device__ __forceinline__ bf16x8 pack8(const float4& lo, const float4& hi) {
    bf16x8 r;
    r[0] = (short)f2bf(lo.x); r[1] = (short)f2bf(lo.y);
    r[2] = (short)f2bf(lo.z); r[3] = (short)f2bf(lo.w);
    r[4] = (short)f2bf(hi.x); r[5] = (short)f2bf(hi.y);
    r[6] = (short)f2bf(hi.z); r[7] = (short)f2bf(hi.w);
    return r;
}

__device__ __forceinline__ float sumsq8(const float4& lo, const float4& hi) {
    return lo.x*lo.x + lo.y*lo.y + lo.z*lo.z + lo.w*lo.w
         + hi.x*hi.x + hi.y*hi.y + hi.z*hi.z + hi.w*hi.w;
}

__global__ __launch_bounds__(BDIM, 4) void pwl_main(
        const float* __restrict__ pred, const float* __restrict__ slots,
        const int* __restrict__ labels, const unsigned char* __restrict__ vmask,
        float* __restrict__ partial) {
    __shared__ float simbuf[NROW][65];
    __shared__ float rnA[NROW], rnB[NROW];
    __shared__ float wsum_f[4], wsum_c[4];

    const int t   = threadIdx.x;
    const int bid = blockIdx.x;          // bid = b*F + f  (matches [B,F,...] layout)
    const int b   = bid >> 5;
    const int f   = bid & 31;
    const float* gA = slots + (size_t)bid * NROW * DDIM;
    const float* gB = pred  + (size_t)bid * NROW * DDIM;

    const int lane = t & 63;
    const int w    = t >> 6;
    const int wr   = (w >> 1) * 32;      // s-quadrant base
    const int wc   = (w & 1) * 32;       // o-quadrant base
    const int lr   = lane & 15;
    const int lk   = (lane >> 4) * 8;

    // per-lane fragment row bases (fp32, direct from global; rows at 2KB stride,
    // 4 lanes (lk=0/8/16/24) cover a contiguous 128B segment per row per step)
    const float* a0p = gA + (size_t)(wr      + lr) * DDIM + lk;
    const float* a1p = gA + (size_t)(wr + 16 + lr) * DDIM + lk;
    const float* b0p = gB + (size_t)(wc      + lr) * DDIM + lk;
    const float* b1p = gB + (size_t)(wc + 16 + lr) * DDIM + lk;

    f32x4 acc00 = {0,0,0,0}, acc01 = {0,0,0,0}, acc10 = {0,0,0,0}, acc11 = {0,0,0,0};
    float sq0 = 0.f, sq1 = 0.f, sq2 = 0.f, sq3 = 0.f;

#pragma unroll
    for (int kk = 0; kk < 16; ++kk) {
        const int off = kk * 32;         // compile-time -> folded into offset: immediates
        const float4 a0lo = *reinterpret_cast<const float4*>(a0p + off);
        const float4 a0hi = *reinterpret_cast<const float4*>(a0p + off + 4);
        const float4 a1lo = *reinterpret_cast<const float4*>(a1p + off);
        const float4 a1hi = *reinterpret_cast<const float4*>(a1p + off + 4);
        const float4 b0lo = *reinterpret_cast<const float4*>(b0p + off);
        const float4 b0hi = *reinterpret_cast<const float4*>(b0p + off + 4);
        const float4 b1lo = *reinterpret_cast<const float4*>(b1p + off);
        const float4 b1hi = *reinterpret_cast<const float4*>(b1p + off + 4);

        sq0 += sumsq8(a0lo, a0hi);
        sq1 += sumsq8(a1lo, a1hi);
        sq2 += sumsq8(b0lo, b0hi);
        sq3 += sumsq8(b1lo, b1hi);

        const bf16x8 A0 = pack8(a0lo, a0hi);
        const bf16x8 A1 = pack8(a1lo, a1hi);
        const bf16x8 B0 = pack8(b0lo, b0hi);
        const bf16x8 B1 = pack8(b1lo, b1hi);

        acc00 = __builtin_amdgcn_mfma_f32_16x16x32_bf16(A0, B0, acc00, 0, 0, 0);
        acc01 = __builtin_amdgcn_mfma_f32_16x16x32_bf16(A0, B1, acc01, 0, 0, 0);
        acc10 = __builtin_amdgcn_mfma_f32_16x16x32_bf16(A1, B0, acc10, 0, 0, 0);
        acc11 = __builtin_amdgcn_mfma_f32_16x16x32_bf16(A1, B1, acc11, 0, 0, 0);
    }

    // full-row sumsq: lanes {lr, lr+16, lr+32, lr+48} hold disjoint k-slices of the same row
    sq0 += __shfl_xor(sq0, 16); sq0 += __shfl_xor(sq0, 32);
    sq1 += __shfl_xor(sq1, 16); sq1 += __shfl_xor(sq1, 32);
    sq2 += __shfl_xor(sq2, 16); sq2 += __shfl_xor(sq2, 32);
    sq3 += __shfl_xor(sq3, 16); sq3 += __shfl_xor(sq3, 32);
    if (lane < 16) {
        if ((w & 1) == 0) {              // w0: A rows 0-31, w2: A rows 32-63
            rnA[wr      + lr] = 1.f / fmaxf(sqrtf(sq0), 1e-12f);
            rnA[wr + 16 + lr] = 1.f / fmaxf(sqrtf(sq1), 1e-12f);
        }
        if (w < 2) {                     // w0: B rows 0-31, w1: B rows 32-63
            rnB[wc      + lr] = 1.f / fmaxf(sqrtf(sq2), 1e-12f);
            rnB[wc + 16 + lr] = 1.f / fmaxf(sqrtf(sq3), 1e-12f);
        }
    }
    __syncthreads();

    // normalize accumulators, write sim to LDS (C/D layout: col=lane&15, row=(lane>>4)*4+j)
    {
        const int r0 = wr + (lane >> 4) * 4;
        const int c0 = wc + lr;
#pragma unroll
        for (int j = 0; j < 4; ++j) {
            simbuf[r0 + j     ][c0     ] = acc00[j] * rnA[r0 + j     ] * rnB[c0     ];
            simbuf[r0 + j     ][c0 + 16] = acc01[j] * rnA[r0 + j     ] * rnB[c0 + 16];
            simbuf[r0 + 16 + j][c0     ] = acc10[j] * rnA[r0 + 16 + j] * rnB[c0     ];
            simbuf[r0 + 16 + j][c0 + 16] = acc11[j] * rnA[r0 + 16 + j] * rnB[c0 + 16];
        }
    }
    __syncthreads();

    // softmax over objects + focal at label; 4 lanes per s-row
    float contrib = 0.f, ccnt = 0.f;
    {
        const int s = t >> 2;
        const int q = t & 3;
        float v[16];
        float mx = -1e30f;
#pragma unroll
        for (int jj = 0; jj < 16; ++jj) {
            v[jj] = simbuf[s][q * 16 + jj];
            mx = fmaxf(mx, v[jj]);
        }
        mx = fmaxf(mx, __shfl_xor(mx, 1));
        mx = fmaxf(mx, __shfl_xor(mx, 2));
        float se = 0.f;
#pragma unroll
        for (int jj = 0; jj < 16; ++jj) se += __expf(v[jj] - mx);
        se += __shfl_xor(se, 1);
        se += __shfl_xor(se, 2);
        if (q == 0) {
            const int lab = labels[(f * BBATCH + b) * NROW + s];
            if (lab >= 0) {
                const float simt  = simbuf[s][lab];
                const float pt    = __expf(simt - mx) / se;
                const float u     = 1.f - pt + 1e-12f;
                const float focal = u * u * __logf(pt + 1e-12f);
                contrib = focal;
                ccnt    = 1.f;
            }
        }
    }
    // wave-level reduce (no LDS/global atomics anywhere)
#pragma unroll
    for (int m = 1; m <= 32; m <<= 1) {
        contrib += __shfl_xor(contrib, m);
        ccnt    += __shfl_xor(ccnt, m);
    }
    if (lane == 0) { wsum_f[w] = contrib; wsum_c[w] = ccnt; }
    __syncthreads();
    if (t == 0) {
        const float rf  = wsum_f[0] + wsum_f[1] + wsum_f[2] + wsum_f[3];
        const float ri  = wsum_c[0] + wsum_c[1] + wsum_c[2] + wsum_c[3];
        const float cnt = fmaxf(ri, 1.f);
        const float nll = -rf / cnt;
        const float vv  = vmask[f * BBATCH + b] ? 1.f : 0.f;
        partial[bid] = 100.f * nll * vv;   // distinct address per block: no contention
    }
}

__global__ __launch_bounds__(BDIM) void pwl_finalize(
        const unsigned char* __restrict__ vmask, const float* __restrict__ partial,
        float* __restrict__ out) {
    __shared__ float sf[4], sv[4];
    const int t = threadIdx.x;
    const float4 p = reinterpret_cast<const float4*>(partial)[t];      // 256*4 = 1024
    float s = p.x + p.y + p.z + p.w;
    const uchar4 mv = reinterpret_cast<const uchar4*>(vmask)[t];       // 256*4 = 1024
    float vs = (mv.x ? 1.f : 0.f) + (mv.y ? 1.f : 0.f) + (mv.z ? 1.f : 0.f) + (mv.w ? 1.f : 0.f);
#pragma unroll
    for (int m = 1; m <= 32; m <<= 1) { s += __shfl_xor(s, m); vs += __shfl_xor(vs, m); }
    if ((t & 63) == 0) { sf[t >> 6] = s; sv[t >> 6] = vs; }
    __syncthreads();
    if (t == 0) {
        const float loss = sf[0] + sf[1] + sf[2] + sf[3];
        const float sums = sv[0] + sv[1] + sv[2] + sv[3];
        out[0] = (sums > 0.f) ? loss / (32.0f * sums) : loss;
    }
}

extern "C" void kernel_launch(void* const* d_in, const int* in_sizes, int n_in,
                              void* d_out, int out_size, void* d_ws, size_t ws_size,
                              hipStream_t stream) {
    const float* pred          = (const float*)d_in[0];
    const float* slots         = (const float*)d_in[1];
    const int* labels          = (const int*)d_in[2];
    const unsigned char* vmask = (const unsigned char*)d_in[3];
    float* out     = (float*)d_out;
    float* partial = (float*)d_ws;   // 1024 floats; every slot written every call

    pwl_main<<<dim3(NBLK), dim3(BDIM), 0, stream>>>(pred, slots, labels, vmask, partial);
    pwl_finalize<<<dim3(1), dim3(BDIM), 0, stream>>>(vmask, partial, out);
}

// Round 6
// 128.522 us; speedup vs baseline: 3.3672x; 3.3672x over previous
//
#include <hip/hip_runtime.h>
#include <hip/hip_bf16.h>

#define BDIM 256
#define NROW 64      // S = O = 64
#define DDIM 512
#define BK 64        // fp32 cols per chunk
#define NCHUNK 8     // 512/64
#define LDK 72       // shorts: 64 + 8 pad -> 144B row stride, 16B aligned
#define FDIM 32
#define BBATCH 32
#define NBLK (FDIM * BBATCH)

typedef short bf16x8 __attribute__((ext_vector_type(8)));
typedef float f32x4 __attribute__((ext_vector_type(4)));

__device__ __forceinline__ unsigned short f2bf(float f) {
    unsigned int u = __float_as_uint(f);
    u += 0x7FFFu + ((u >> 16) & 1u);   // round-to-nearest-even
    return (unsigned short)(u >> 16);
}

__device__ __forceinline__ ushort4 pack4(const float4& v) {
    ushort4 r;
    r.x = f2bf(v.x); r.y = f2bf(v.y); r.z = f2bf(v.z); r.w = f2bf(v.w);
    return r;
}

__device__ __forceinline__ float sumsq4(const float4& v) {
    return v.x*v.x + v.y*v.y + v.z*v.z + v.w*v.w;
}

__global__ __launch_bounds__(BDIM, 4) void pwl_main(
        const float* __restrict__ pred, const float* __restrict__ slots,
        const int* __restrict__ labels, const unsigned char* __restrict__ vmask,
        float* __restrict__ partial) {
    // double-buffered bf16 staging; simbuf overlays the front of the buffer
    // (only written after the post-MFMA barrier)
    __shared__ __align__(16) unsigned char smem[4 * NROW * LDK * sizeof(unsigned short)];
    unsigned short (*lA)[NROW][LDK] = reinterpret_cast<unsigned short(*)[NROW][LDK]>(smem);
    unsigned short (*lB)[NROW][LDK] = reinterpret_cast<unsigned short(*)[NROW][LDK]>(
        smem + 2 * NROW * LDK * sizeof(unsigned short));
    float (*simbuf)[65] = reinterpret_cast<float(*)[65]>(smem);  // 16640 <= 36864

    __shared__ float rnA[NROW], rnB[NROW];
    __shared__ float wsum_f[4], wsum_c[4];

    const int t   = threadIdx.x;
    const int bid = blockIdx.x;          // bid = b*F + f  (matches [B,F,...] layout)
    const int b   = bid >> 5;
    const int f   = bid & 31;
    const float* gA = slots + (size_t)bid * NROW * DDIM;
    const float* gB = pred  + (size_t)bid * NROW * DDIM;

    const int lane = t & 63;
    const int w    = t >> 6;
    const int wr   = (w >> 1) * 32;      // s-quadrant base
    const int wc   = (w & 1) * 32;       // o-quadrant base
    const int lr   = lane & 15;
    const int lk   = (lane >> 4) * 8;
    const int tr   = t >> 4;             // staging row-class (0..15)
    const int ts   = t & 15;             // staging slot (float4 index in 64-col chunk)

    f32x4 acc00 = {0,0,0,0}, acc01 = {0,0,0,0}, acc10 = {0,0,0,0}, acc11 = {0,0,0,0};
    float sqa[4], sqb[4];
#pragma unroll
    for (int i = 0; i < 4; ++i) { sqa[i] = 0.f; sqb[i] = 0.f; }

    // depth-1 register prefetch: 4+4 float4 = 32 VGPRs (R2 spilled with 64)
    float4 va[4], vb[4];
#pragma unroll
    for (int i = 0; i < 4; ++i) {
        const int row = i * 16 + tr;
        va[i] = *reinterpret_cast<const float4*>(gA + (size_t)row * DDIM + ts * 4);
        vb[i] = *reinterpret_cast<const float4*>(gB + (size_t)row * DDIM + ts * 4);
    }

#pragma unroll
    for (int c = 0; c < NCHUNK; ++c) {
        const int p = c & 1;
        // consume prefetched regs: sumsq + cvt + LDS write
#pragma unroll
        for (int i = 0; i < 4; ++i) {
            const int row = i * 16 + tr;
            sqa[i] += sumsq4(va[i]);
            sqb[i] += sumsq4(vb[i]);
            *reinterpret_cast<ushort4*>(&lA[p][row][ts * 4]) = pack4(va[i]);
            *reinterpret_cast<ushort4*>(&lB[p][row][ts * 4]) = pack4(vb[i]);
        }
        // issue next chunk's loads (regs now free) — in flight across barrier+MFMA
        if (c + 1 < NCHUNK) {
            const int cb = (c + 1) * BK;
#pragma unroll
            for (int i = 0; i < 4; ++i) {
                const int row = i * 16 + tr;
                va[i] = *reinterpret_cast<const float4*>(gA + (size_t)row * DDIM + cb + ts * 4);
                vb[i] = *reinterpret_cast<const float4*>(gB + (size_t)row * DDIM + cb + ts * 4);
            }
        }
        // single barrier per chunk: next write goes to the OTHER buffer, and the
        // barrier of iteration c+1 orders this iteration's MFMA reads vs c+2's write
        __syncthreads();
#pragma unroll
        for (int kk = 0; kk < 2; ++kk) {
            const int kb = kk * 32 + lk;
            const bf16x8 a0 = *reinterpret_cast<const bf16x8*>(&lA[p][wr      + lr][kb]);
            const bf16x8 a1 = *reinterpret_cast<const bf16x8*>(&lA[p][wr + 16 + lr][kb]);
            const bf16x8 b0 = *reinterpret_cast<const bf16x8*>(&lB[p][wc      + lr][kb]);
            const bf16x8 b1 = *reinterpret_cast<const bf16x8*>(&lB[p][wc + 16 + lr][kb]);
            acc00 = __builtin_amdgcn_mfma_f32_16x16x32_bf16(a0, b0, acc00, 0, 0, 0);
            acc01 = __builtin_amdgcn_mfma_f32_16x16x32_bf16(a0, b1, acc01, 0, 0, 0);
            acc10 = __builtin_amdgcn_mfma_f32_16x16x32_bf16(a1, b0, acc10, 0, 0, 0);
            acc11 = __builtin_amdgcn_mfma_f32_16x16x32_bf16(a1, b1, acc11, 0, 0, 0);
        }
    }

    // row sumsq: row r's partials live in the 16 threads t = (r%16)*16 + s
    // (one 16-lane group of one wave) -> shfl reduce over s
#pragma unroll
    for (int i = 0; i < 4; ++i) {
        float x = sqa[i], y = sqb[i];
#pragma unroll
        for (int m = 1; m <= 8; m <<= 1) { x += __shfl_xor(x, m); y += __shfl_xor(y, m); }
        if (ts == 0) {
            const int row = i * 16 + tr;
            rnA[row] = 1.f / fmaxf(sqrtf(x), 1e-12f);
            rnB[row] = 1.f / fmaxf(sqrtf(y), 1e-12f);
        }
    }
    __syncthreads();   // all MFMA done -> simbuf (overlaying lA) safe to write

    // normalize accumulators, write sim to LDS (C/D layout: col=lane&15, row=(lane>>4)*4+j)
    {
        const int r0 = wr + (lane >> 4) * 4;
        const int c0 = wc + lr;
#pragma unroll
        for (int j = 0; j < 4; ++j) {
            simbuf[r0 + j     ][c0     ] = acc00[j] * rnA[r0 + j     ] * rnB[c0     ];
            simbuf[r0 + j     ][c0 + 16] = acc01[j] * rnA[r0 + j     ] * rnB[c0 + 16];
            simbuf[r0 + 16 + j][c0     ] = acc10[j] * rnA[r0 + 16 + j] * rnB[c0     ];
            simbuf[r0 + 16 + j][c0 + 16] = acc11[j] * rnA[r0 + 16 + j] * rnB[c0 + 16];
        }
    }
    __syncthreads();

    // softmax over objects + focal at label; 4 lanes per s-row
    float contrib = 0.f, ccnt = 0.f;
    {
        const int s = t >> 2;
        const int q = t & 3;
        float v[16];
        float mx = -1e30f;
#pragma unroll
        for (int jj = 0; jj < 16; ++jj) {
            v[jj] = simbuf[s][q * 16 + jj];
            mx = fmaxf(mx, v[jj]);
        }
        mx = fmaxf(mx, __shfl_xor(mx, 1));
        mx = fmaxf(mx, __shfl_xor(mx, 2));
        float se = 0.f;
#pragma unroll
        for (int jj = 0; jj < 16; ++jj) se += __expf(v[jj] - mx);
        se += __shfl_xor(se, 1);
        se += __shfl_xor(se, 2);
        if (q == 0) {
            const int lab = labels[(f * BBATCH + b) * NROW + s];
            if (lab >= 0) {
                const float simt  = simbuf[s][lab];
                const float pt    = __expf(simt - mx) / se;
                const float u     = 1.f - pt + 1e-12f;
                const float focal = u * u * __logf(pt + 1e-12f);
                contrib = focal;
                ccnt    = 1.f;
            }
        }
    }
    // wave-level reduce (no LDS/global atomics anywhere)
#pragma unroll
    for (int m = 1; m <= 32; m <<= 1) {
        contrib += __shfl_xor(contrib, m);
        ccnt    += __shfl_xor(ccnt, m);
    }
    if (lane == 0) { wsum_f[w] = contrib; wsum_c[w] = ccnt; }
    __syncthreads();
    if (t == 0) {
        const float rf  = wsum_f[0] + wsum_f[1] + wsum_f[2] + wsum_f[3];
        const float ri  = wsum_c[0] + wsum_c[1] + wsum_c[2] + wsum_c[3];
        const float cnt = fmaxf(ri, 1.f);
        const float nll = -rf / cnt;
        const float vv  = vmask[f * BBATCH + b] ? 1.f : 0.f;
        partial[bid] = 100.f * nll * vv;   // distinct address per block: no contention
    }
}

__global__ __launch_bounds__(BDIM) void pwl_finalize(
        const unsigned char* __restrict__ vmask, const float* __restrict__ partial,
        float* __restrict__ out) {
    __shared__ float sf[4], sv[4];
    const int t = threadIdx.x;
    const float4 p = reinterpret_cast<const float4*>(partial)[t];      // 256*4 = 1024
    float s = p.x + p.y + p.z + p.w;
    const uchar4 mv = reinterpret_cast<const uchar4*>(vmask)[t];       // 256*4 = 1024
    float vs = (mv.x ? 1.f : 0.f) + (mv.y ? 1.f : 0.f) + (mv.z ? 1.f : 0.f) + (mv.w ? 1.f : 0.f);
#pragma unroll
    for (int m = 1; m <= 32; m <<= 1) { s += __shfl_xor(s, m); vs += __shfl_xor(vs, m); }
    if ((t & 63) == 0) { sf[t >> 6] = s; sv[t >> 6] = vs; }
    __syncthreads();
    if (t == 0) {
        const float loss = sf[0] + sf[1] + sf[2] + sf[3];
        const float sums = sv[0] + sv[1] + sv[2] + sv[3];
        out[0] = (sums > 0.f) ? loss / (32.0f * sums) : loss;
    }
}

extern "C" void kernel_launch(void* const* d_in, const int* in_sizes, int n_in,
                              void* d_out, int out_size, void* d_ws, size_t ws_size,
                              hipStream_t stream) {
    const float* pred          = (const float*)d_in[0];
    const float* slots         = (const float*)d_in[1];
    const int* labels          = (const int*)d_in[2];
    const unsigned char* vmask = (const unsigned char*)d_in[3];
    float* out     = (float*)d_out;
    float* partial = (float*)d_ws;   // 1024 floats; every slot written every call

    pwl_main<<<dim3(NBLK), dim3(BDIM), 0, stream>>>(pred, slots, labels, vmask, partial);
    pwl_finalize<<<dim3(1), dim3(BDIM), 0, stream>>>(vmask, partial, out);
}